// Round 9
// baseline (220.058 us; speedup 1.0000x reference)
//
#include <hip/hip_runtime.h>
#include <hip/hip_bf16.h>
#include <cstdint>

// CIN layer chain: B=1024, F0=32, EMB=64, layer sizes 128/128/128.
// cur[b,k,e] = sum_{i,j} x[b,i,e] * h[b,j,e] * W[i*fi+j, k]
// Per batch: C(128 x 64) = W^T (128 x fan_in) @ Z (fan_in x 64),
//   Z[(i,j),e] = x[b,i,e]*h[b,j,e]  (built on the fly in B-fragments).
//
// R9: DMA/compute overlap. R4-R8 all ~43-48 us regardless of waves/SIMD
// (1.3/2/4) or LDS-read volume -> residual is the W-DMA issued right
// before the barrier that drains it (m97 vmcnt(0) stall, ~600 cyc x 16
// iters). Now: wave=batch (grid 256, 4 batches/block, M=128 x N=64/wave,
// no split-K, no combine), double-buffered sW (2 x 8 KB), DMA for chunk
// it+1 issued BEFORE computing chunk it (~1200 cyc of slack). x read
// from global per chunk (no sX). One fused pack kernel.

typedef _Float16 half8  __attribute__((ext_vector_type(8)));
typedef _Float16 half4_ __attribute__((ext_vector_type(4)));
typedef _Float16 half2_ __attribute__((ext_vector_type(2)));
typedef float    f32x4  __attribute__((ext_vector_type(4)));

__device__ __forceinline__ void load_lds16(const void* g, void* l) {
    __builtin_amdgcn_global_load_lds(
        reinterpret_cast<const __attribute__((address_space(1))) unsigned*>(
            reinterpret_cast<uintptr_t>(g)),
        reinterpret_cast<__attribute__((address_space(3))) unsigned*>(
            reinterpret_cast<uintptr_t>(l)),
        16, 0, 0);
}

// Fused pack: W (fan_in,128) f32 -> chunked f16 Wt[c][m][kk] = W[c*32+kk][m]
// blocks 0..31 -> W0, 32..95 -> W1, 96..159 -> W2.
__global__ void pack_w_all(const float* __restrict__ W0, _Float16* __restrict__ Wt0,
                           const float* __restrict__ W1, _Float16* __restrict__ Wt1,
                           const float* __restrict__ W2, _Float16* __restrict__ Wt2)
{
    __shared__ _Float16 ldsT[128 * 33];
    const int blk = blockIdx.x, t = threadIdx.x;
    const float* W;
    _Float16* Wt;
    int c;
    if (blk < 32)       { W = W0; Wt = Wt0; c = blk; }
    else if (blk < 96)  { W = W1; Wt = Wt1; c = blk - 32; }
    else                { W = W2; Wt = Wt2; c = blk - 96; }

    for (int p = t; p < 32 * 128; p += 256) {
        int kk = p >> 7, m = p & 127;
        ldsT[m * 33 + kk] = (_Float16)W[(size_t)(c * 32 + kk) * 128 + m];
    }
    __syncthreads();
    int m = t >> 1, kk0 = (t & 1) * 16;
    half8 v0, v1;
#pragma unroll
    for (int i = 0; i < 8; ++i) {
        v0[i] = ldsT[m * 33 + kk0 + i];
        v1[i] = ldsT[m * 33 + kk0 + 8 + i];
    }
    *(half8*)(Wt + (size_t)c * 4096 + t * 16)     = v0;
    *(half8*)(Wt + (size_t)c * 4096 + t * 16 + 8) = v1;
}

// One CIN layer. Block = 4 batches, 256 threads (4 waves), wave = batch.
// Wave tile: M=128 (all k_out) x N=64 (all e), full K. Double-buffered sW.
__global__ __launch_bounds__(256, 1)
void cin_layer(const float* __restrict__ x,         // (1024,32,64) f32
               const _Float16* __restrict__ h_in,   // (B,64,72) padded image, null => use x
               const _Float16* __restrict__ Wt,     // chunked [c][128][32] f16
               const float* __restrict__ bias,      // (128) f32
               _Float16* __restrict__ h_out,        // (B,64,72) padded image or null
               float* __restrict__ out,             // (1024,256) f32
               int fi, int ishift, int nchunks, int ph, int direct_m0, int out_base)
{
    __shared__ alignas(16) char smem[53248];
    _Float16* sW = (_Float16*)smem;              // 16 KB: 2 bufs x 4096 halves
    _Float16* sH = (_Float16*)(smem + 16384);    // 36 KB: hT [w][e*ph + j] (4 batches)

    const int t    = threadIdx.x;
    const int lane = t & 63;
    const int w    = t >> 6;          // wave = batch-within-block
    const int lr   = lane & 15;
    const int q    = lane >> 4;
    const int b0   = blockIdx.x * 4;

    // Prologue: stage chunk 0 into buf 0.
    {
        const char* wsrc = (const char*)Wt;
        char* wdst = (char*)sW;
        load_lds16(wsrc + t * 16, wdst + t * 16);
        load_lds16(wsrc + 4096 + t * 16, wdst + 4096 + t * 16);
    }
    // Stage hidden images (4 batches).
    if (h_in) {
        const char* src = (const char*)(h_in + (size_t)b0 * 4608);
        char* dst = (char*)sH;
        for (int off = t * 16; off < 36864; off += 4096)
            load_lds16(src + off, dst + off);
    } else {
        // layer 0: hidden = x; build hT [e][j], pitch ph=40, 4 batches
        const float4* xv = (const float4*)(x + (size_t)b0 * 2048);
#pragma unroll
        for (int s = 0; s < 8; ++s) {
            int p4 = t + s * 256;                 // 2048 float4 = 4 batches
            float4 v = xv[p4];
            int bb2 = p4 >> 9, idx = (p4 & 511) * 4;
            int i = idx >> 6, e0 = idx & 63;
            _Float16* hb = sH + bb2 * (ph << 6);
            hb[(e0 + 0) * ph + i] = (_Float16)v.x;
            hb[(e0 + 1) * ph + i] = (_Float16)v.y;
            hb[(e0 + 2) * ph + i] = (_Float16)v.z;
            hb[(e0 + 3) * ph + i] = (_Float16)v.w;
        }
    }
    __syncthreads();

    const _Float16* aPb = sW + lr * 32 + q * 8;                 // + buf*4096 + mt*512
    const _Float16* hP  = sH + w * (ph << 6) + lr * ph + q * 8; // + nt*16*ph + j0
    const float*    xb  = x + (size_t)(b0 + w) * 2048 + lr;     // + i*64 + nt*16

    f32x4 acc[8][4] = {};

    for (int it = 0; it < nchunks; ++it) {
        // Issue DMA for chunk it+1 into the other buffer BEFORE computing
        // chunk it — ~1200 cyc of MFMA slack hides the L2->LDS latency.
        if (it + 1 < nchunks) {
            const char* wsrc = (const char*)Wt + (size_t)(it + 1) * 8192;
            char* wdst = (char*)sW + ((it + 1) & 1) * 8192;
            load_lds16(wsrc + t * 16, wdst + t * 16);
            load_lds16(wsrc + 4096 + t * 16, wdst + 4096 + t * 16);
        }

        const int i  = it >> ishift;           // x-field of this chunk
        const int j0 = (it - (i << ishift)) << 5;

        half8 bf[4];
#pragma unroll
        for (int nt = 0; nt < 4; ++nt) {
            half8 hv = *(const half8*)(hP + nt * (ph << 4) + j0);
            float xs = xb[(i << 6) + (nt << 4)];
            _Float16 xh = (_Float16)xs;
            half2_ xv2 = { xh, xh };
            half8 xv8 = __builtin_shufflevector(xv2, xv2, 0, 1, 0, 1, 0, 1, 0, 1);
            bf[nt] = hv * xv8;
        }
        const _Float16* aP = aPb + (it & 1) * 4096;
#pragma unroll
        for (int mt = 0; mt < 8; ++mt) {
            half8 af = *(const half8*)(aP + mt * 512);
#pragma unroll
            for (int nt = 0; nt < 4; ++nt)
                acc[mt][nt] = __builtin_amdgcn_mfma_f32_16x16x32_f16(
                    af, bf[nt], acc[mt][nt], 0, 0, 0);
        }
        __syncthreads();   // drains DMA(it+1) — issued one full phase ago
    }

    // ---- epilogue (wave owns its whole batch: no cross-wave combine) ----
    const int batch = b0 + w;

    if (h_out != nullptr) {
        // hidden rows 0..63: acc + bias -> padded f16 image [e*72 + j]
#pragma unroll
        for (int mt = 0; mt < 4; ++mt)
#pragma unroll
            for (int nt = 0; nt < 4; ++nt) {
                int e = nt * 16 + lr;
                int j = mt * 16 + q * 4;
                half4_ vh;
#pragma unroll
                for (int r = 0; r < 4; ++r)
                    vh[r] = (_Float16)(acc[mt][nt][r] + bias[j + r]);
                *(half4_*)(h_out + (size_t)batch * 4608 + e * 72 + j) = vh;
            }
    }
    // direct rows m >= direct_m0: reduce over all 64 e, + 64*bias
#pragma unroll
    for (int mt = 0; mt < 8; ++mt) {
        if ((mt << 4) >= direct_m0) {
            f32x4 s = acc[mt][0] + acc[mt][1] + acc[mt][2] + acc[mt][3];
#pragma unroll
            for (int r = 0; r < 4; ++r) {
                float v = s[r];
                v += __shfl_xor(v, 1);
                v += __shfl_xor(v, 2);
                v += __shfl_xor(v, 4);
                v += __shfl_xor(v, 8);
                if (lr == 0) {
                    int m = (mt << 4) + q * 4 + r;
                    out[(size_t)batch * 256 + out_base + (m - direct_m0)]
                        = v + 64.0f * bias[m];
                }
            }
        }
    }
}

extern "C" void kernel_launch(void* const* d_in, const int* in_sizes, int n_in,
                              void* d_out, int out_size, void* d_ws, size_t ws_size,
                              hipStream_t stream)
{
    const float* x  = (const float*)d_in[0];
    const float* W0 = (const float*)d_in[1];
    const float* b0 = (const float*)d_in[2];
    const float* W1 = (const float*)d_in[3];
    const float* b1 = (const float*)d_in[4];
    const float* W2 = (const float*)d_in[5];
    const float* b2 = (const float*)d_in[6];
    float* out = (float*)d_out;

    char* ws = (char*)d_ws;
    _Float16* Wt0 = (_Float16*)(ws + 0);                        // 256 KB
    _Float16* Wt1 = (_Float16*)(ws + 262144);                   // 512 KB
    _Float16* Wt2 = (_Float16*)(ws + 786432);                   // 512 KB
    _Float16* h1  = (_Float16*)(ws + 1310720);                  // 1024*4608*2 = 9 MB
    _Float16* h2  = (_Float16*)(ws + 1310720 + 9437184);        // 9 MB
    (void)in_sizes; (void)n_in; (void)out_size; (void)ws_size;

    hipLaunchKernelGGL(pack_w_all, dim3(160), dim3(256), 0, stream,
                       W0, Wt0, W1, Wt1, W2, Wt2);

    // layer 0: fi=32 (hidden = x), direct rows m in [64,128) -> out cols 0..63
    hipLaunchKernelGGL(cin_layer, dim3(256), dim3(256), 0, stream,
                       x, (const _Float16*)nullptr, Wt0, b0, h1, out,
                       32, 0, 32, 40, 64, 0);
    // layer 1: fi=64, direct rows -> out cols 64..127
    hipLaunchKernelGGL(cin_layer, dim3(256), dim3(256), 0, stream,
                       x, (const _Float16*)h1, Wt1, b1, h2, out,
                       64, 1, 64, 72, 64, 64);
    // layer 2: fi=64, all 128 rows direct -> out cols 128..255
    hipLaunchKernelGGL(cin_layer, dim3(256), dim3(256), 0, stream,
                       x, (const _Float16*)h2, Wt2, b2, (_Float16*)nullptr, out,
                       64, 1, 64, 72, 0, 128);
}

// Round 10
// 172.767 us; speedup vs baseline: 1.2737x; 1.2737x over previous
//
#include <hip/hip_runtime.h>
#include <hip/hip_bf16.h>
#include <cstdint>

// CIN layer chain: B=1024, F0=32, EMB=64, layer sizes 128/128/128.
// cur[b,k,e] = sum_{i,j} x[b,i,e] * h[b,j,e] * W[i*fi+j, k]
// Per batch: C(128 x 64) = W^T (128 x fan_in) @ Z (fan_in x 64),
//   Z[(i,j),e] = x[b,i,e]*h[b,j,e]  (built on the fly in B-fragments).
//
// R10: barrier-free K-loop. R9 proved the in-loop __syncthreads drains the
// prefetch DMA (vmcnt(0) before s_barrier waits on ALL loads) — the
// 2-barrier staging structure cannot pipeline. Fix: A-fragments read
// directly from global Wt (L1-hot, permuted-contiguous 1KB/instr), LDS
// only for h/x (read-only after one prologue barrier). Wave = (batch x
// m-half), M=64 x N=64, full K, register double-buffered software
// pipeline (afA/afB, hvA/hvB) — no barriers, fine-grained vmcnt/lgkm.

typedef _Float16 half8  __attribute__((ext_vector_type(8)));
typedef _Float16 half4_ __attribute__((ext_vector_type(4)));
typedef _Float16 half2_ __attribute__((ext_vector_type(2)));
typedef float    f32x4  __attribute__((ext_vector_type(4)));
typedef unsigned short ushort4_ __attribute__((ext_vector_type(4)));

__device__ __forceinline__ void load_lds16(const void* g, void* l) {
    __builtin_amdgcn_global_load_lds(
        reinterpret_cast<const __attribute__((address_space(1))) unsigned*>(
            reinterpret_cast<uintptr_t>(g)),
        reinterpret_cast<__attribute__((address_space(3))) unsigned*>(
            reinterpret_cast<uintptr_t>(l)),
        16, 0, 0);
}

__device__ __forceinline__ unsigned short f16bits(float v) {
    return __builtin_bit_cast(unsigned short, (_Float16)v);
}

// Fused pack: W (fan_in,128) f32 -> chunked f16 Wt[c][m][kk] = W[c*32+kk][m].
// blocks 0..31 -> W0, 32..95 -> W1, 96..159 -> W2.
__global__ void pack_w_all(const float* __restrict__ W0, _Float16* __restrict__ Wt0,
                           const float* __restrict__ W1, _Float16* __restrict__ Wt1,
                           const float* __restrict__ W2, _Float16* __restrict__ Wt2)
{
    __shared__ _Float16 ldsT[128 * 33];
    const int blk = blockIdx.x, t = threadIdx.x;
    const float* W;
    _Float16* Wt;
    int c;
    if (blk < 32)       { W = W0; Wt = Wt0; c = blk; }
    else if (blk < 96)  { W = W1; Wt = Wt1; c = blk - 32; }
    else                { W = W2; Wt = Wt2; c = blk - 96; }

    for (int p = t; p < 32 * 128; p += 256) {
        int kk = p >> 7, m = p & 127;
        ldsT[m * 33 + kk] = (_Float16)W[(size_t)(c * 32 + kk) * 128 + m];
    }
    __syncthreads();
    int m = t >> 1, kk0 = (t & 1) * 16;
    half8 v0, v1;
#pragma unroll
    for (int i = 0; i < 8; ++i) {
        v0[i] = ldsT[m * 33 + kk0 + i];
        v1[i] = ldsT[m * 33 + kk0 + 8 + i];
    }
    *(half8*)(Wt + (size_t)c * 4096 + t * 16)     = v0;
    *(half8*)(Wt + (size_t)c * 4096 + t * 16 + 8) = v1;
}

// One CIN layer. Block = 2 batches, 256 threads (4 waves).
// Wave w: mh=w&1 (m-half), bb=w>>1 (batch). Wave tile M=64 x N=64, full K.
__global__ __launch_bounds__(256, 2)
void cin_layer(const float* __restrict__ x,         // (1024,32,64) f32
               const _Float16* __restrict__ h_in,   // (B,64,72) padded image, null => use x
               const _Float16* __restrict__ Wt,     // chunked [c][128][32] f16
               const float* __restrict__ bias,      // (128) f32
               _Float16* __restrict__ h_out,        // (B,64,72) padded image or null
               float* __restrict__ out,             // (1024,256) f32
               int ishift, int nchunks, int ph, int direct_m0, int out_base)
{
    __shared__ alignas(16) char smem[26624];
    _Float16* sH        = (_Float16*)smem;                 // 18 KB: hT [bb][e*ph + j]
    unsigned short* sXu = (unsigned short*)(smem + 18432); // 8 KB: x f16 bits [bb][i*64+e]

    const int t    = threadIdx.x;
    const int lane = t & 63;
    const int w    = t >> 6;
    const int mh   = w & 1;
    const int bb   = w >> 1;
    const int lr   = lane & 15;
    const int q    = lane >> 4;
    const int b0   = blockIdx.x * 2;

    // ---- prologue staging (one barrier total) ----
    {
        const float4* xv = (const float4*)(x + (size_t)b0 * 2048);
#pragma unroll
        for (int s = 0; s < 4; ++s) {
            int p4 = t + s * 256;          // 1024 float4 = 2 batches
            float4 v = xv[p4];
            ushort4_ d;
            d[0] = f16bits(v.x); d[1] = f16bits(v.y);
            d[2] = f16bits(v.z); d[3] = f16bits(v.w);
            *(ushort4_*)(sXu + p4 * 4) = d;
            if (!h_in) {
                // layer 0: hidden = x; build hT [e][j], pitch ph=40
                int bb2 = p4 >> 9, idx = (p4 & 511) * 4;
                int i = idx >> 6, e0 = idx & 63;
                _Float16* hb = sH + bb2 * (ph << 6);
                hb[(e0 + 0) * ph + i] = (_Float16)v.x;
                hb[(e0 + 1) * ph + i] = (_Float16)v.y;
                hb[(e0 + 2) * ph + i] = (_Float16)v.z;
                hb[(e0 + 3) * ph + i] = (_Float16)v.w;
            }
        }
    }
    if (h_in) {
        const char* src = (const char*)(h_in + (size_t)b0 * 4608);
        char* dst = (char*)sH;
        for (int off = t * 16; off < 18432; off += 4096)
            load_lds16(src + off, dst + off);
    }
    __syncthreads();   // the ONLY barrier

    // ---- barrier-free pipelined K-loop ----
    const _Float16* aG       = Wt + (mh * 64 + lr) * 32 + q * 8;     // + c*4096 + mt*512
    const _Float16* hP       = sH + bb * (ph << 6) + lr * ph + q * 8; // + nt*16*ph + j0
    const unsigned short* xP = sXu + bb * 2048 + lr;                  // + i*64 + nt*16

    f32x4 acc[4][4] = {};
    half8 afA[4], afB[4], hvA[4], hvB[4];
    unsigned short xuA[4], xuB[4];

    // prefetch chunk 0 (i=0, j0=0)
#pragma unroll
    for (int mt = 0; mt < 4; ++mt) afA[mt] = *(const half8*)(aG + mt * 512);
#pragma unroll
    for (int nt = 0; nt < 4; ++nt) {
        hvA[nt] = *(const half8*)(hP + nt * (ph << 4));
        xuA[nt] = xP[nt << 4];
    }

    for (int it = 0; it < nchunks; it += 2) {
        // prefetch chunk it+1 into B (nchunks even -> always valid)
        {
            const int c  = it + 1;
            const int i  = c >> ishift;
            const int j0 = (c - (i << ishift)) << 5;
            const _Float16* ag = aG + (size_t)c * 4096;
#pragma unroll
            for (int mt = 0; mt < 4; ++mt) afB[mt] = *(const half8*)(ag + mt * 512);
#pragma unroll
            for (int nt = 0; nt < 4; ++nt) {
                hvB[nt] = *(const half8*)(hP + nt * (ph << 4) + j0);
                xuB[nt] = xP[(i << 6) + (nt << 4)];
            }
        }
        // compute chunk it from A regs
#pragma unroll
        for (int nt = 0; nt < 4; ++nt) {
            unsigned du = (unsigned)xuA[nt] * 0x10001u;
            half2_ xv2 = __builtin_bit_cast(half2_, du);
            half8 xv8 = __builtin_shufflevector(xv2, xv2, 0, 1, 0, 1, 0, 1, 0, 1);
            half8 bf = hvA[nt] * xv8;
#pragma unroll
            for (int mt = 0; mt < 4; ++mt)
                acc[mt][nt] = __builtin_amdgcn_mfma_f32_16x16x32_f16(
                    afA[mt], bf, acc[mt][nt], 0, 0, 0);
        }
        // prefetch chunk it+2 into A
        if (it + 2 < nchunks) {
            const int c  = it + 2;
            const int i  = c >> ishift;
            const int j0 = (c - (i << ishift)) << 5;
            const _Float16* ag = aG + (size_t)c * 4096;
#pragma unroll
            for (int mt = 0; mt < 4; ++mt) afA[mt] = *(const half8*)(ag + mt * 512);
#pragma unroll
            for (int nt = 0; nt < 4; ++nt) {
                hvA[nt] = *(const half8*)(hP + nt * (ph << 4) + j0);
                xuA[nt] = xP[(i << 6) + (nt << 4)];
            }
        }
        // compute chunk it+1 from B regs
#pragma unroll
        for (int nt = 0; nt < 4; ++nt) {
            unsigned du = (unsigned)xuB[nt] * 0x10001u;
            half2_ xv2 = __builtin_bit_cast(half2_, du);
            half8 xv8 = __builtin_shufflevector(xv2, xv2, 0, 1, 0, 1, 0, 1, 0, 1);
            half8 bf = hvB[nt] * xv8;
#pragma unroll
            for (int mt = 0; mt < 4; ++mt)
                acc[mt][nt] = __builtin_amdgcn_mfma_f32_16x16x32_f16(
                    afB[mt], bf, acc[mt][nt], 0, 0, 0);
        }
    }

    // ---- epilogue (wave-private, no cross-wave combine) ----
    const int batch = b0 + bb;

    if (h_out != nullptr && mh == 0) {
        // hidden rows 0..63: acc + bias -> padded f16 image [e*72 + j]
#pragma unroll
        for (int mt = 0; mt < 4; ++mt)
#pragma unroll
            for (int nt = 0; nt < 4; ++nt) {
                int e = nt * 16 + lr;
                int j = mt * 16 + q * 4;
                half4_ vh;
#pragma unroll
                for (int r = 0; r < 4; ++r)
                    vh[r] = (_Float16)(acc[mt][nt][r] + bias[j + r]);
                *(half4_*)(h_out + (size_t)batch * 4608 + e * 72 + j) = vh;
            }
    }
    // direct rows (global m = mh*64 + mt*16 + q*4 + r >= direct_m0)
#pragma unroll
    for (int mt = 0; mt < 4; ++mt) {
        if (mh * 64 + (mt << 4) >= direct_m0) {
            f32x4 s = acc[mt][0] + acc[mt][1] + acc[mt][2] + acc[mt][3];
#pragma unroll
            for (int r = 0; r < 4; ++r) {
                float v = s[r];
                v += __shfl_xor(v, 1);
                v += __shfl_xor(v, 2);
                v += __shfl_xor(v, 4);
                v += __shfl_xor(v, 8);
                if (lr == 0) {
                    int m = mh * 64 + (mt << 4) + q * 4 + r;
                    out[(size_t)batch * 256 + out_base + (m - direct_m0)]
                        = v + 64.0f * bias[m];
                }
            }
        }
    }
}

extern "C" void kernel_launch(void* const* d_in, const int* in_sizes, int n_in,
                              void* d_out, int out_size, void* d_ws, size_t ws_size,
                              hipStream_t stream)
{
    const float* x  = (const float*)d_in[0];
    const float* W0 = (const float*)d_in[1];
    const float* b0 = (const float*)d_in[2];
    const float* W1 = (const float*)d_in[3];
    const float* b1 = (const float*)d_in[4];
    const float* W2 = (const float*)d_in[5];
    const float* b2 = (const float*)d_in[6];
    float* out = (float*)d_out;

    char* ws = (char*)d_ws;
    _Float16* Wt0 = (_Float16*)(ws + 0);                        // 256 KB
    _Float16* Wt1 = (_Float16*)(ws + 262144);                   // 512 KB
    _Float16* Wt2 = (_Float16*)(ws + 786432);                   // 512 KB
    _Float16* h1  = (_Float16*)(ws + 1310720);                  // 1024*4608*2 = 9 MB
    _Float16* h2  = (_Float16*)(ws + 1310720 + 9437184);        // 9 MB
    (void)in_sizes; (void)n_in; (void)out_size; (void)ws_size;

    hipLaunchKernelGGL(pack_w_all, dim3(160), dim3(256), 0, stream,
                       W0, Wt0, W1, Wt1, W2, Wt2);

    // layer 0: fi=32 (hidden = x), i=c (ishift=0), direct -> out cols 0..63
    hipLaunchKernelGGL(cin_layer, dim3(512), dim3(256), 0, stream,
                       x, (const _Float16*)nullptr, Wt0, b0, h1, out,
                       0, 32, 40, 64, 0);
    // layer 1: fi=64 (ishift=1), direct -> out cols 64..127
    hipLaunchKernelGGL(cin_layer, dim3(512), dim3(256), 0, stream,
                       x, (const _Float16*)h1, Wt1, b1, h2, out,
                       1, 64, 72, 64, 64);
    // layer 2: fi=64, all 128 rows direct -> out cols 128..255
    hipLaunchKernelGGL(cin_layer, dim3(512), dim3(256), 0, stream,
                       x, (const _Float16*)h2, Wt2, b2, (_Float16*)nullptr, out,
                       1, 64, 72, 0, 128);
}